// Round 3
// baseline (2066.311 us; speedup 1.0000x reference)
//
#include <hip/hip_runtime.h>
#include <hip/hip_bf16.h>

typedef __bf16 bf16x8_t __attribute__((ext_vector_type(8)));
typedef __bf16 bf16x4_t __attribute__((ext_vector_type(4)));
typedef short s16x4_t  __attribute__((ext_vector_type(4)));
typedef float f32x4_t  __attribute__((ext_vector_type(4)));

#define NB 2
#define NS 2048
#define NHID 3584
#define NHEADS 16
#define NKVH 8
#define DH 256
#define WIN 1024

__device__ __forceinline__ float bf2f(ushort u) {
  union { unsigned v; float f; } x; x.v = ((unsigned)u) << 16; return x.f;
}
__device__ __forceinline__ ushort f2bf(float f) {
  unsigned x = __builtin_bit_cast(unsigned, f);
  unsigned r = (x + 0x7fffu + ((x >> 16) & 1u)) >> 16;
  return (ushort)r;
}

__device__ __forceinline__ f32x4_t mfma_pv(s16x4_t a, s16x4_t b, f32x4_t c) {
#if __has_builtin(__builtin_amdgcn_mfma_f32_16x16x16_bf16)
  return __builtin_amdgcn_mfma_f32_16x16x16_bf16(
      __builtin_bit_cast(bf16x4_t, a), __builtin_bit_cast(bf16x4_t, b), c, 0, 0, 0);
#else
  return __builtin_amdgcn_mfma_f32_16x16x16bf16_1k(a, b, c, 0, 0, 0);
#endif
}

// ---------------- f32 -> bf16 elementwise convert (x4 vectorized) ---------
__global__ __launch_bounds__(256) void f32_to_bf16_kernel(const float* __restrict__ in,
                                                          ushort* __restrict__ out, int n4) {
  int i = (int)blockIdx.x * 256 + (int)threadIdx.x;
  if (i < n4) {
    float4 v = ((const float4*)in)[i];
    ushort4 o;
    o.x = f2bf(v.x); o.y = f2bf(v.y); o.z = f2bf(v.z); o.w = f2bf(v.w);
    ((ushort4*)out)[i] = o;
  }
}

// ------------- transpose+convert: f32 in[R][C] -> bf16 out[C][R] ----------
__global__ __launch_bounds__(256) void transpose_f32_bf16(const float* __restrict__ in,
                                                          ushort* __restrict__ out,
                                                          int R, int Cc) {
  __shared__ ushort tile[64][72];
  const int t = threadIdx.x;
  const int ct = Cc >> 6;
  const int by = blockIdx.x / ct;
  const int bx = blockIdx.x % ct;
  const int r0 = by << 6, c0 = bx << 6;
#pragma unroll
  for (int i = 0; i < 16; ++i) {
    int idx = i * 256 + t;
    int r = idx >> 6, c = idx & 63;
    tile[r][c] = f2bf(in[(size_t)(r0 + r) * Cc + c0 + c]);
  }
  __syncthreads();
#pragma unroll
  for (int i = 0; i < 16; ++i) {
    int idx = i * 256 + t;
    int rr = idx >> 6, cc = idx & 63;
    out[(size_t)(c0 + rr) * R + r0 + cc] = tile[cc][rr];
  }
}

// ---------------- GEMM: C[M][N] = A[M][K] * Bt[N][K]^T, bf16 in, f32 acc
// 128x128 tile, BK=64, 4 waves (2x2), each wave 64x64 via 4x4 16x16 frags.
// LDS row-major [128][64] bf16, XOR swizzle byte^=((row&7)<<4).
// EPI=0: bf16 C[row*N+col]. EPI=1: V-transpose -> bf16 vt[(b*8+kvh)*256+d][s].
// EPI=2: f32 C[row*N+col].
template <int EPI>
__global__ __launch_bounds__(256) void gemm_bt(const ushort* __restrict__ A,
                                               const ushort* __restrict__ Bt,
                                               void* __restrict__ Cout,
                                               int M, int N, int K) {
  __shared__ alignas(16) char lA[128 * 128];
  __shared__ alignas(16) char lB[128 * 128];
  const int t = threadIdx.x;
  const int lane = t & 63;
  const int wid = t >> 6;
  const int wm = (wid >> 1) << 6;
  const int wn = (wid & 1) << 6;
  const int g = lane >> 4;
  const int lr = lane & 15;
  const int nbn = N >> 7;
  const int bm = (int)blockIdx.x / nbn;
  const int bn = (int)blockIdx.x % nbn;
  const int m0 = bm << 7, n0 = bn << 7;

  f32x4_t acc[4][4] = {};

  const int nkt = K >> 6;
  for (int kt = 0; kt < nkt; ++kt) {
    const int k0 = kt << 6;
    uint4 ra[4], rb[4];
#pragma unroll
    for (int i = 0; i < 4; ++i) {
      int c = i * 256 + t;
      int row = c >> 3;
      int col = (c & 7) << 3;
      ra[i] = *(const uint4*)(A + (size_t)(m0 + row) * K + (k0 + col));
      rb[i] = *(const uint4*)(Bt + (size_t)(n0 + row) * K + (k0 + col));
    }
    __syncthreads();
#pragma unroll
    for (int i = 0; i < 4; ++i) {
      int c = i * 256 + t;
      int row = c >> 3;
      int off = (row << 7) + ((c & 7) << 4);
      int sw = (row & 7) << 4;
      *(uint4*)(lA + (off ^ sw)) = ra[i];
      *(uint4*)(lB + (off ^ sw)) = rb[i];
    }
    __syncthreads();
#pragma unroll
    for (int ks = 0; ks < 2; ++ks) {
      bf16x8_t af[4], bfv[4];
#pragma unroll
      for (int mi = 0; mi < 4; ++mi) {
        int row = wm + (mi << 4) + lr;
        af[mi] = *(const bf16x8_t*)(lA + (((row << 7) + (ks << 6) + (g << 4)) ^ ((row & 7) << 4)));
      }
#pragma unroll
      for (int nj = 0; nj < 4; ++nj) {
        int row = wn + (nj << 4) + lr;
        bfv[nj] = *(const bf16x8_t*)(lB + (((row << 7) + (ks << 6) + (g << 4)) ^ ((row & 7) << 4)));
      }
#pragma unroll
      for (int mi = 0; mi < 4; ++mi)
#pragma unroll
        for (int nj = 0; nj < 4; ++nj)
          acc[mi][nj] = __builtin_amdgcn_mfma_f32_16x16x32_bf16(af[mi], bfv[nj], acc[mi][nj], 0, 0, 0);
    }
  }

  if (EPI == 0) {
    ushort* C = (ushort*)Cout;
#pragma unroll
    for (int mi = 0; mi < 4; ++mi) {
#pragma unroll
      for (int nj = 0; nj < 4; ++nj) {
        int col = n0 + wn + (nj << 4) + lr;
#pragma unroll
        for (int r = 0; r < 4; ++r) {
          int row = m0 + wm + (mi << 4) + (g << 2) + r;
          C[(size_t)row * N + col] = f2bf(acc[mi][nj][r]);
        }
      }
    }
  } else if (EPI == 1) {
    ushort* C = (ushort*)Cout;
#pragma unroll
    for (int mi = 0; mi < 4; ++mi) {
      int row0 = m0 + wm + (mi << 4) + (g << 2);
      int bb = row0 >> 11;
      int ss = row0 & (NS - 1);
#pragma unroll
      for (int nj = 0; nj < 4; ++nj) {
        int col = n0 + wn + (nj << 4) + lr;
        int kvh = col >> 8;
        int d = col & 255;
        ushort4 st;
        st.x = f2bf(acc[mi][nj][0]);
        st.y = f2bf(acc[mi][nj][1]);
        st.z = f2bf(acc[mi][nj][2]);
        st.w = f2bf(acc[mi][nj][3]);
        *(ushort4*)(C + ((size_t)((bb * NKVH + kvh) * DH + d)) * NS + ss) = st;
      }
    }
  } else {
    float* Cf = (float*)Cout;
#pragma unroll
    for (int mi = 0; mi < 4; ++mi) {
#pragma unroll
      for (int nj = 0; nj < 4; ++nj) {
        int col = n0 + wn + (nj << 4) + lr;
#pragma unroll
        for (int r = 0; r < 4; ++r) {
          int row = m0 + wm + (mi << 4) + (g << 2) + r;
          Cf[(size_t)row * N + col] = acc[mi][nj][r];
        }
      }
    }
  }
}

// ---------------- RoPE in-place on bf16 [B*S][nheads*256], pairs (d,d+128) -
__global__ __launch_bounds__(256) void rope_kernel(ushort* __restrict__ buf,
                                                   const float* __restrict__ sint,
                                                   const float* __restrict__ cost,
                                                   int nheads) {
  int idx = (int)blockIdx.x * 256 + (int)threadIdx.x;
  int d = idx & 127;
  int h = (idx >> 7) % nheads;
  int tok = idx / (nheads << 7);
  int pos = tok & (NS - 1);
  float c = cost[pos * DH + d];
  float s = sint[pos * DH + d];
  size_t base = (size_t)tok * ((size_t)nheads * DH) + h * DH + d;
  float x1 = bf2f(buf[base]);
  float x2 = bf2f(buf[base + 128]);
  buf[base] = f2bf(x1 * c - x2 * s);
  buf[base + 128] = f2bf(x2 * c + x1 * s);
}

// ---------------- flash attention, sliding window + softcap ----------------
// grid: B*NH*(S/64); block 256 = 4 waves, each wave 16 q-rows.
// Swapped QK^T: S^T = mfma(K, Q); P^T lands in 16x16x16 A-operand layout.
__global__ __launch_bounds__(256) void attn_kernel(const ushort* __restrict__ q,
                                                   const ushort* __restrict__ k,
                                                   const ushort* __restrict__ vt,
                                                   ushort* __restrict__ ao) {
  __shared__ alignas(16) char lK[32 * 512];  // [32 keys][256 d] bf16, swz ((row&7)<<4)
  __shared__ alignas(16) char lV[256 * 64];  // [256 d][32 keys] bf16, swz ((d&7)<<3)
  const int bid = (int)blockIdx.x;
  const int qb = bid & 31;
  const int h = (bid >> 5) & 15;
  const int b = bid >> 9;
  const int kvh = h >> 1;
  const int qb0 = qb << 6;
  const int t = threadIdx.x;
  const int lane = t & 63;
  const int w = t >> 6;
  const int g = lane >> 4;
  const int lr = lane & 15;

  const int qrow = qb0 + (w << 4) + lr;  // this lane's query (B-operand col)
  bf16x8_t qf[8];
  const ushort* qbase = q + (size_t)(b * NS + qrow) * (NHEADS * DH) + h * DH;
#pragma unroll
  for (int ks = 0; ks < 8; ++ks)
    qf[ks] = *(const bf16x8_t*)(qbase + (ks << 5) + (g << 3));

  float m_r = -1e30f, l_r = 0.f;
  f32x4_t oacc[16] = {};

  const int qminw = qb0 + (w << 4);
  const int qmaxw = qminw + 15;
  int t_lo = qb0 - (WIN - 1);
  if (t_lo < 0) t_lo = 0;
  t_lo &= ~31;
  const int t_hi = qb0 + 63;

  for (int kt = t_lo; kt <= t_hi; kt += 32) {
    __syncthreads();
#pragma unroll
    for (int i = 0; i < 4; ++i) {  // stage K tile [32][256]
      int c = i * 256 + t;
      int row = c >> 5;
      int cb = c & 31;
      uint4 val = *(const uint4*)(k + (size_t)(b * NS + kt + row) * (NKVH * DH) + kvh * DH + (cb << 3));
      *(uint4*)(lK + (((row << 9) + (cb << 4)) ^ ((row & 7) << 4))) = val;
    }
#pragma unroll
    for (int i = 0; i < 4; ++i) {  // stage V^T tile [256][32]
      int c = i * 256 + t;
      int d = c >> 2;
      int kk = (c & 3) << 3;
      uint4 val = *(const uint4*)(vt + ((size_t)((b * NKVH + kvh) * DH + d)) * NS + kt + kk);
      int base = (d << 6) + (kk << 1);
      int sw = (d & 7) << 3;
      uint2 lo; lo.x = val.x; lo.y = val.y;
      uint2 hi; hi.x = val.z; hi.y = val.w;
      *(uint2*)(lV + (base ^ sw)) = lo;
      *(uint2*)(lV + ((base + 8) ^ sw)) = hi;
    }
    __syncthreads();

#pragma unroll
    for (int sub = 0; sub < 2; ++sub) {
      const int key0 = kt + (sub << 4);
      if (key0 > qmaxw) continue;                    // fully above causal for wave
      if (key0 + 15 < qminw - (WIN - 1)) continue;   // fully below window for wave

      f32x4_t sacc = {};
#pragma unroll
      for (int ks = 0; ks < 8; ++ks) {
        int row = (sub << 4) + lr;
        bf16x8_t kf = *(const bf16x8_t*)(lK + (((row << 9) + (ks << 6) + (g << 4)) ^ ((row & 7) << 4)));
        sacc = __builtin_amdgcn_mfma_f32_16x16x32_bf16(kf, qf[ks], sacc, 0, 0, 0);
      }

      float sv[4];
      float mx = -1e30f;
#pragma unroll
      for (int r = 0; r < 4; ++r) {
        // scale 1/16, softcap 50*tanh(x/50)
        float x = sacc[r] * (1.0f / (16.0f * 50.0f));
        float e = __expf(fminf(fmaxf(2.0f * x, -80.0f), 80.0f));
        float cap = 50.0f * __fdividef(e - 1.0f, e + 1.0f);
        int key = key0 + (g << 2) + r;
        bool ok = (key <= qrow) && (qrow - key < WIN);
        sv[r] = ok ? cap : -1e30f;
        mx = fmaxf(mx, sv[r]);
      }
      mx = fmaxf(mx, __shfl_xor(mx, 16));
      mx = fmaxf(mx, __shfl_xor(mx, 32));
      float mnew = fmaxf(m_r, mx);
      float alpha = __expf(m_r - mnew);
      float psum = 0.f;
      float pvv[4];
#pragma unroll
      for (int r = 0; r < 4; ++r) {
        float p = (sv[r] > -1e29f) ? __expf(sv[r] - mnew) : 0.f;
        pvv[r] = p;
        psum += p;
      }
      psum += __shfl_xor(psum, 16);
      psum += __shfl_xor(psum, 32);
      l_r = l_r * alpha + psum;
      m_r = mnew;

      float ar0 = __shfl(alpha, (g << 2) + 0);
      float ar1 = __shfl(alpha, (g << 2) + 1);
      float ar2 = __shfl(alpha, (g << 2) + 2);
      float ar3 = __shfl(alpha, (g << 2) + 3);
      bool need = (ar0 != 1.f) || (ar1 != 1.f) || (ar2 != 1.f) || (ar3 != 1.f);
      if (__any(need)) {
#pragma unroll
        for (int dt = 0; dt < 16; ++dt) {
          oacc[dt][0] *= ar0;
          oacc[dt][1] *= ar1;
          oacc[dt][2] *= ar2;
          oacc[dt][3] *= ar3;
        }
      }

      s16x4_t pa;
      pa[0] = (short)f2bf(pvv[0]);
      pa[1] = (short)f2bf(pvv[1]);
      pa[2] = (short)f2bf(pvv[2]);
      pa[3] = (short)f2bf(pvv[3]);

      const int kk = (sub << 4) + (g << 2);
#pragma unroll
      for (int dt = 0; dt < 16; ++dt) {
        int d = (dt << 4) + lr;
        s16x4_t vf = *(const s16x4_t*)(lV + (((d << 6) + (kk << 1)) ^ ((d & 7) << 3)));
        oacc[dt] = mfma_pv(pa, vf, oacc[dt]);
      }
    }
  }

  float dn[4];
#pragma unroll
  for (int r = 0; r < 4; ++r) {
    float lv = __shfl(l_r, (g << 2) + r);
    dn[r] = 1.0f / lv;
  }
  const int orow0 = b * NS + qb0 + (w << 4) + (g << 2);
#pragma unroll
  for (int dt = 0; dt < 16; ++dt) {
    int col = h * DH + (dt << 4) + lr;
#pragma unroll
    for (int r = 0; r < 4; ++r) {
      ao[(size_t)(orow0 + r) * (NHEADS * DH) + col] = f2bf(oacc[dt][r] * dn[r]);
    }
  }
}

extern "C" void kernel_launch(void* const* d_in, const int* in_sizes, int n_in,
                              void* d_out, int out_size, void* d_ws, size_t ws_size,
                              hipStream_t stream) {
  const float* hs   = (const float*)d_in[0];
  const float* sint = (const float*)d_in[3];
  const float* cost = (const float*)d_in[4];
  const float* Wq = (const float*)d_in[6];
  const float* Wk = (const float*)d_in[7];
  const float* Wv = (const float*)d_in[8];
  const float* Wo = (const float*)d_in[9];

  char* ws = (char*)d_ws;
  size_t off = 0;
  auto alloc = [&](size_t bytes) {
    char* p = ws + off;
    off += (bytes + 255) & ~(size_t)255;
    return p;
  };
  ushort* hsb   = (ushort*)alloc((size_t)4096 * 3584 * 2);  // hs in bf16
  ushort* wT    = (ushort*)alloc((size_t)4096 * 3584 * 2);  // reused weight^T buffer
  ushort* qbuf  = (ushort*)alloc((size_t)4096 * 4096 * 2);
  ushort* kbuf  = (ushort*)alloc((size_t)4096 * 2048 * 2);
  ushort* vtbuf = (ushort*)alloc((size_t)4096 * 2048 * 2);
  ushort* aobuf = qbuf;  // alias: attn writes exactly the region only it reads
  if (off > ws_size) return;  // ws too small: leaves output zeroed (visible failure)

  // hs f32 -> bf16
  f32_to_bf16_kernel<<<(4096 * 3584 / 4) / 256, 256, 0, stream>>>(hs, hsb, 4096 * 3584 / 4);

  // Q projection
  transpose_f32_bf16<<<(3584 / 64) * (4096 / 64), 256, 0, stream>>>(Wq, wT, 3584, 4096);
  gemm_bt<0><<<32 * 32, 256, 0, stream>>>(hsb, wT, qbuf, 4096, 4096, 3584);

  // K projection
  transpose_f32_bf16<<<(3584 / 64) * (2048 / 64), 256, 0, stream>>>(Wk, wT, 3584, 2048);
  gemm_bt<0><<<32 * 16, 256, 0, stream>>>(hsb, wT, kbuf, 4096, 2048, 3584);

  // V projection (writes V^T layout)
  transpose_f32_bf16<<<(3584 / 64) * (2048 / 64), 256, 0, stream>>>(Wv, wT, 3584, 2048);
  gemm_bt<1><<<32 * 16, 256, 0, stream>>>(hsb, wT, vtbuf, 4096, 2048, 3584);

  // RoPE (q then k), in-place
  rope_kernel<<<(4096 * 16 * 128) / 256, 256, 0, stream>>>(qbuf, sint, cost, 16);
  rope_kernel<<<(4096 * 8 * 128) / 256, 256, 0, stream>>>(kbuf, sint, cost, 8);

  // attention (ao aliases qbuf)
  attn_kernel<<<NB * NHEADS * (NS / 64), 256, 0, stream>>>(qbuf, kbuf, vtbuf, aobuf);

  // output projection, f32 out
  transpose_f32_bf16<<<(4096 / 64) * (3584 / 64), 256, 0, stream>>>(Wo, wT, 4096, 3584);
  gemm_bt<2><<<32 * 28, 256, 0, stream>>>(aobuf, wT, d_out, 4096, 3584, 4096);
}

// Round 5
// 917.089 us; speedup vs baseline: 2.2531x; 2.2531x over previous
//
#include <hip/hip_runtime.h>
#include <hip/hip_bf16.h>

typedef __bf16 bf16x8_t __attribute__((ext_vector_type(8)));
typedef __bf16 bf16x4_t __attribute__((ext_vector_type(4)));
typedef short s16x4_t  __attribute__((ext_vector_type(4)));
typedef float f32x4_t  __attribute__((ext_vector_type(4)));

#define NB 2
#define NS 2048
#define NHID 3584
#define NHEADS 16
#define NKVH 8
#define DH 256
#define WIN 1024

__device__ __forceinline__ float bf2f(ushort u) {
  union { unsigned v; float f; } x; x.v = ((unsigned)u) << 16; return x.f;
}
__device__ __forceinline__ ushort f2bf(float f) {
  unsigned x = __builtin_bit_cast(unsigned, f);
  unsigned r = (x + 0x7fffu + ((x >> 16) & 1u)) >> 16;
  return (ushort)r;
}

__device__ __forceinline__ void gload16(const void* g, void* l) {
  __builtin_amdgcn_global_load_lds((const __attribute__((address_space(1))) void*)g,
                                   (__attribute__((address_space(3))) void*)l, 16, 0, 0);
}

__device__ __forceinline__ f32x4_t mfma_pv(s16x4_t a, s16x4_t b, f32x4_t c) {
#if __has_builtin(__builtin_amdgcn_mfma_f32_16x16x16_bf16)
  return __builtin_amdgcn_mfma_f32_16x16x16_bf16(
      __builtin_bit_cast(bf16x4_t, a), __builtin_bit_cast(bf16x4_t, b), c, 0, 0, 0);
#else
  return __builtin_amdgcn_mfma_f32_16x16x16bf16_1k(a, b, c, 0, 0, 0);
#endif
}

// ---------------- f32 -> bf16 elementwise convert (x4 vectorized) ---------
__global__ __launch_bounds__(256) void f32_to_bf16_kernel(const float* __restrict__ in,
                                                          ushort* __restrict__ out, int n4) {
  int i = (int)blockIdx.x * 256 + (int)threadIdx.x;
  if (i < n4) {
    float4 v = ((const float4*)in)[i];
    ushort4 o;
    o.x = f2bf(v.x); o.y = f2bf(v.y); o.z = f2bf(v.z); o.w = f2bf(v.w);
    ((ushort4*)out)[i] = o;
  }
}

// ------------- transpose+convert: f32 in[R][C] -> bf16 out[C][R] ----------
__global__ __launch_bounds__(256) void transpose_f32_bf16(const float* __restrict__ in,
                                                          ushort* __restrict__ out,
                                                          int R, int Cc) {
  __shared__ ushort tile[64][72];
  const int t = threadIdx.x;
  const int ct = Cc >> 6;
  const int by = blockIdx.x / ct;
  const int bx = blockIdx.x % ct;
  const int r0 = by << 6, c0 = bx << 6;
#pragma unroll
  for (int i = 0; i < 16; ++i) {
    int idx = i * 256 + t;
    int r = idx >> 6, c = idx & 63;
    tile[r][c] = f2bf(in[(size_t)(r0 + r) * Cc + c0 + c]);
  }
  __syncthreads();
#pragma unroll
  for (int i = 0; i < 16; ++i) {
    int idx = i * 256 + t;
    int rr = idx >> 6, cc = idx & 63;
    out[(size_t)(c0 + rr) * R + r0 + cc] = tile[cc][rr];
  }
}

// ---------------- GEMM: C[M][N] = A[M][K] * Bt[N][K]^T, bf16 in, f32 acc
// m97 structure: 128x128 tile, BK=64, 4 waves (2x2), global_load_lds width-16
// staging (linear LDS dest, inverse-swizzled global source chunk=(l&7)^(l>>3)),
// swizzled ds_read_b128 (byte ^= (row&7)<<4). Epilogues bounce through LDS and
// issue wide dwordx4 stores.
// EPI=0: bf16 C[row*N+col]. EPI=1: bf16 vt[(b*8+kvh)*256+d][s]. EPI=2: f32 C.
template <int EPI>
__global__ __launch_bounds__(256, 2) void gemm_bt(const ushort* __restrict__ A,
                                                  const ushort* __restrict__ Bt,
                                                  void* __restrict__ Cout,
                                                  int M, int N, int K) {
  __shared__ alignas(16) char lds[32768];  // lA = lds[0:16K), lB = lds[16K:32K)
  const int t = threadIdx.x;
  const int lane = t & 63;
  const int w = t >> 6;
  const int g = lane >> 4;
  const int lr = lane & 15;
  const int wm = (w >> 1) << 6;
  const int wn = (w & 1) << 6;

  // bijective XCD swizzle (gridDim.x % 8 == 0 for all call sites)
  const int nbn = N >> 7;
  const int nwg = (int)gridDim.x;
  const int bid = (int)blockIdx.x;
  const int swz = (bid & 7) * (nwg >> 3) + (bid >> 3);
  const int bm = swz / nbn, bn = swz % nbn;
  const int m0 = bm << 7, n0 = bn << 7;

  // staging source: wave w stages rows [w*32, w*32+32), 8 rows per issue.
  // physical LDS chunk (l&7) at row-local (l>>3) must hold logical chunk
  // (l&7)^(row&7); row&7 == l>>3 here, so source chunk = (l&7)^(l>>3).
  const int srow = (w << 5) + (lane >> 3);
  const int schunk = (lane & 7) ^ (lane >> 3);
  const ushort* pa = A + (size_t)(m0 + srow) * K + (schunk << 3);
  const ushort* pb = Bt + (size_t)(n0 + srow) * K + (schunk << 3);
  char* ldst = lds + ((w << 5) << 7);  // (w*32)*128 bytes

  f32x4_t acc[4][4] = {};

  const int nkt = K >> 6;
  for (int kt = 0; kt < nkt; ++kt) {
    const int koff = kt << 6;
    __syncthreads();  // previous tile's reads complete before overwrite
#pragma unroll
    for (int j = 0; j < 4; ++j) {
      gload16(pa + (size_t)(j << 3) * K + koff, ldst + (j << 10));
      gload16(pb + (size_t)(j << 3) * K + koff, ldst + 16384 + (j << 10));
    }
    __syncthreads();  // compiler drains vmcnt(0) before s_barrier
#pragma unroll
    for (int ks = 0; ks < 2; ++ks) {
      bf16x8_t af[4], bfv[4];
#pragma unroll
      for (int mi = 0; mi < 4; ++mi) {
        int row = wm + (mi << 4) + lr;
        af[mi] = *(const bf16x8_t*)(lds + (((row << 7) + (ks << 6) + (g << 4)) ^ ((row & 7) << 4)));
      }
#pragma unroll
      for (int nj = 0; nj < 4; ++nj) {
        int row = wn + (nj << 4) + lr;
        bfv[nj] = *(const bf16x8_t*)(lds + 16384 + (((row << 7) + (ks << 6) + (g << 4)) ^ ((row & 7) << 4)));
      }
#pragma unroll
      for (int mi = 0; mi < 4; ++mi)
#pragma unroll
        for (int nj = 0; nj < 4; ++nj)
          acc[mi][nj] = __builtin_amdgcn_mfma_f32_16x16x32_bf16(af[mi], bfv[nj], acc[mi][nj], 0, 0, 0);
    }
  }

  // ---- epilogue: stage whole 128x128 bf16 tile in LDS, then wide stores ----
  __syncthreads();
  if (EPI == 1) {
    // stage TRANSPOSED: lds[col][row]
#pragma unroll
    for (int mi = 0; mi < 4; ++mi)
#pragma unroll
      for (int nj = 0; nj < 4; ++nj) {
        int col = wn + (nj << 4) + lr;
#pragma unroll
        for (int r = 0; r < 4; ++r) {
          int row = wm + (mi << 4) + (g << 2) + r;
          *(ushort*)(lds + (((col << 8) + (row << 1)) ^ ((col & 7) << 4))) = f2bf(acc[mi][nj][r]);
        }
      }
  } else {
#pragma unroll
    for (int mi = 0; mi < 4; ++mi)
#pragma unroll
      for (int nj = 0; nj < 4; ++nj) {
        int col = wn + (nj << 4) + lr;
#pragma unroll
        for (int r = 0; r < 4; ++r) {
          int row = wm + (mi << 4) + (g << 2) + r;
          *(ushort*)(lds + (((row << 8) + (col << 1)) ^ ((row & 7) << 4))) = f2bf(acc[mi][nj][r]);
        }
      }
  }
  __syncthreads();

  if (EPI == 0) {
    ushort* C = (ushort*)Cout;
#pragma unroll
    for (int it = 0; it < 8; ++it) {
      int idx = it * 256 + t;
      int row = idx >> 4, ch = idx & 15;
      uint4 v = *(const uint4*)(lds + (((row << 8) + (ch << 4)) ^ ((row & 7) << 4)));
      *(uint4*)(C + (size_t)(m0 + row) * N + n0 + (ch << 3)) = v;
    }
  } else if (EPI == 1) {
    ushort* C = (ushort*)Cout;
    const int bb = m0 >> 11;
    const int ss = m0 & (NS - 1);
#pragma unroll
    for (int it = 0; it < 8; ++it) {
      int idx = it * 256 + t;
      int dc = idx >> 4, ch = idx & 15;
      uint4 v = *(const uint4*)(lds + (((dc << 8) + (ch << 4)) ^ ((dc & 7) << 4)));
      int gc = n0 + dc;
      int kvh = gc >> 8, d = gc & 255;
      *(uint4*)(C + ((size_t)((bb * NKVH + kvh) * DH + d)) * NS + ss + (ch << 3)) = v;
    }
  } else {
    float* Cf = (float*)Cout;
#pragma unroll
    for (int it = 0; it < 16; ++it) {
      int idx = it * 256 + t;
      int row = idx >> 5, qd = idx & 31;
      ushort4 hv = *(const ushort4*)(lds + (((row << 8) + (qd << 3)) ^ ((row & 7) << 4)));
      float4 fv;
      fv.x = bf2f(hv.x); fv.y = bf2f(hv.y); fv.z = bf2f(hv.z); fv.w = bf2f(hv.w);
      *(float4*)(Cf + (size_t)(m0 + row) * N + n0 + (qd << 2)) = fv;
    }
  }
}

// ---------------- RoPE in-place on bf16 [B*S][nheads*256], pairs (d,d+128) -
__global__ __launch_bounds__(256) void rope_kernel(ushort* __restrict__ buf,
                                                   const float* __restrict__ sint,
                                                   const float* __restrict__ cost,
                                                   int nheads) {
  int idx = (int)blockIdx.x * 256 + (int)threadIdx.x;
  int d = idx & 127;
  int h = (idx >> 7) % nheads;
  int tok = idx / (nheads << 7);
  int pos = tok & (NS - 1);
  float c = cost[pos * DH + d];
  float s = sint[pos * DH + d];
  size_t base = (size_t)tok * ((size_t)nheads * DH) + h * DH + d;
  float x1 = bf2f(buf[base]);
  float x2 = bf2f(buf[base + 128]);
  buf[base] = f2bf(x1 * c - x2 * s);
  buf[base + 128] = f2bf(x2 * c + x1 * s);
}

// ---------------- flash attention, sliding window + softcap ----------------
// grid: B*NH*(S/64); block 256 = 4 waves, each wave 16 q-rows.
// Swapped QK^T: S^T = mfma(K, Q); P^T lands in 16x16x16 A-operand layout.
__global__ __launch_bounds__(256) void attn_kernel(const ushort* __restrict__ q,
                                                   const ushort* __restrict__ k,
                                                   const ushort* __restrict__ vt,
                                                   ushort* __restrict__ ao) {
  __shared__ alignas(16) char lK[32 * 512];  // [32 keys][256 d] bf16, swz ((row&7)<<4)
  __shared__ alignas(16) char lV[256 * 64];  // [256 d][32 keys] bf16, swz ((d&7)<<3)
  const int bid = (int)blockIdx.x;
  const int qb = bid & 31;
  const int h = (bid >> 5) & 15;
  const int b = bid >> 9;
  const int kvh = h >> 1;
  const int qb0 = qb << 6;
  const int t = threadIdx.x;
  const int lane = t & 63;
  const int w = t >> 6;
  const int g = lane >> 4;
  const int lr = lane & 15;

  const int qrow = qb0 + (w << 4) + lr;  // this lane's query (B-operand col)
  bf16x8_t qf[8];
  const ushort* qbase = q + (size_t)(b * NS + qrow) * (NHEADS * DH) + h * DH;
#pragma unroll
  for (int ks = 0; ks < 8; ++ks)
    qf[ks] = *(const bf16x8_t*)(qbase + (ks << 5) + (g << 3));

  float m_r = -1e30f, l_r = 0.f;
  f32x4_t oacc[16] = {};

  const int qminw = qb0 + (w << 4);
  const int qmaxw = qminw + 15;
  int t_lo = qb0 - (WIN - 1);
  if (t_lo < 0) t_lo = 0;
  t_lo &= ~31;
  const int t_hi = qb0 + 63;

  for (int kt = t_lo; kt <= t_hi; kt += 32) {
    __syncthreads();
#pragma unroll
    for (int i = 0; i < 4; ++i) {  // stage K tile [32][256]
      int c = i * 256 + t;
      int row = c >> 5;
      int cb = c & 31;
      uint4 val = *(const uint4*)(k + (size_t)(b * NS + kt + row) * (NKVH * DH) + kvh * DH + (cb << 3));
      *(uint4*)(lK + (((row << 9) + (cb << 4)) ^ ((row & 7) << 4))) = val;
    }
#pragma unroll
    for (int i = 0; i < 4; ++i) {  // stage V^T tile [256][32]
      int c = i * 256 + t;
      int d = c >> 2;
      int kk = (c & 3) << 3;
      uint4 val = *(const uint4*)(vt + ((size_t)((b * NKVH + kvh) * DH + d)) * NS + kt + kk);
      int base = (d << 6) + (kk << 1);
      int sw = (d & 7) << 3;
      uint2 lo; lo.x = val.x; lo.y = val.y;
      uint2 hi; hi.x = val.z; hi.y = val.w;
      *(uint2*)(lV + (base ^ sw)) = lo;
      *(uint2*)(lV + ((base + 8) ^ sw)) = hi;
    }
    __syncthreads();

#pragma unroll
    for (int sub = 0; sub < 2; ++sub) {
      const int key0 = kt + (sub << 4);
      if (key0 > qmaxw) continue;                    // fully above causal for wave
      if (key0 + 15 < qminw - (WIN - 1)) continue;   // fully below window for wave

      f32x4_t sacc = {};
#pragma unroll
      for (int ks = 0; ks < 8; ++ks) {
        int row = (sub << 4) + lr;
        bf16x8_t kf = *(const bf16x8_t*)(lK + (((row << 9) + (ks << 6) + (g << 4)) ^ ((row & 7) << 4)));
        sacc = __builtin_amdgcn_mfma_f32_16x16x32_bf16(kf, qf[ks], sacc, 0, 0, 0);
      }

      float sv[4];
      float mx = -1e30f;
#pragma unroll
      for (int r = 0; r < 4; ++r) {
        // scale 1/16, softcap 50*tanh(x/50)
        float x = sacc[r] * (1.0f / (16.0f * 50.0f));
        float e = __expf(fminf(fmaxf(2.0f * x, -80.0f), 80.0f));
        float cap = 50.0f * __fdividef(e - 1.0f, e + 1.0f);
        int key = key0 + (g << 2) + r;
        bool ok = (key <= qrow) && (qrow - key < WIN);
        sv[r] = ok ? cap : -1e30f;
        mx = fmaxf(mx, sv[r]);
      }
      mx = fmaxf(mx, __shfl_xor(mx, 16));
      mx = fmaxf(mx, __shfl_xor(mx, 32));
      float mnew = fmaxf(m_r, mx);
      float alpha = __expf(m_r - mnew);
      float psum = 0.f;
      float pvv[4];
#pragma unroll
      for (int r = 0; r < 4; ++r) {
        float p = (sv[r] > -1e29f) ? __expf(sv[r] - mnew) : 0.f;
        pvv[r] = p;
        psum += p;
      }
      psum += __shfl_xor(psum, 16);
      psum += __shfl_xor(psum, 32);
      l_r = l_r * alpha + psum;
      m_r = mnew;

      float ar0 = __shfl(alpha, (g << 2) + 0);
      float ar1 = __shfl(alpha, (g << 2) + 1);
      float ar2 = __shfl(alpha, (g << 2) + 2);
      float ar3 = __shfl(alpha, (g << 2) + 3);
      bool need = (ar0 != 1.f) || (ar1 != 1.f) || (ar2 != 1.f) || (ar3 != 1.f);
      if (__any(need)) {
#pragma unroll
        for (int dt = 0; dt < 16; ++dt) {
          oacc[dt][0] *= ar0;
          oacc[dt][1] *= ar1;
          oacc[dt][2] *= ar2;
          oacc[dt][3] *= ar3;
        }
      }

      s16x4_t pa;
      pa[0] = (short)f2bf(pvv[0]);
      pa[1] = (short)f2bf(pvv[1]);
      pa[2] = (short)f2bf(pvv[2]);
      pa[3] = (short)f2bf(pvv[3]);

      const int kk = (sub << 4) + (g << 2);
#pragma unroll
      for (int dt = 0; dt < 16; ++dt) {
        int d = (dt << 4) + lr;
        s16x4_t vf = *(const s16x4_t*)(lV + (((d << 6) + (kk << 1)) ^ ((d & 7) << 3)));
        oacc[dt] = mfma_pv(pa, vf, oacc[dt]);
      }
    }
  }

  float dn[4];
#pragma unroll
  for (int r = 0; r < 4; ++r) {
    float lv = __shfl(l_r, (g << 2) + r);
    dn[r] = 1.0f / lv;
  }
  const int orow0 = b * NS + qb0 + (w << 4) + (g << 2);
#pragma unroll
  for (int dt = 0; dt < 16; ++dt) {
    int col = h * DH + (dt << 4) + lr;
#pragma unroll
    for (int r = 0; r < 4; ++r) {
      ao[(size_t)(orow0 + r) * (NHEADS * DH) + col] = f2bf(oacc[dt][r] * dn[r]);
    }
  }
}

extern "C" void kernel_launch(void* const* d_in, const int* in_sizes, int n_in,
                              void* d_out, int out_size, void* d_ws, size_t ws_size,
                              hipStream_t stream) {
  const float* hs   = (const float*)d_in[0];
  const float* sint = (const float*)d_in[3];
  const float* cost = (const float*)d_in[4];
  const float* Wq = (const float*)d_in[6];
  const float* Wk = (const float*)d_in[7];
  const float* Wv = (const float*)d_in[8];
  const float* Wo = (const float*)d_in[9];

  char* ws = (char*)d_ws;
  size_t off = 0;
  auto alloc = [&](size_t bytes) {
    char* p = ws + off;
    off += (bytes + 255) & ~(size_t)255;
    return p;
  };
  ushort* hsb   = (ushort*)alloc((size_t)4096 * 3584 * 2);  // hs in bf16
  ushort* wT    = (ushort*)alloc((size_t)4096 * 3584 * 2);  // reused weight^T buffer
  ushort* qbuf  = (ushort*)alloc((size_t)4096 * 4096 * 2);
  ushort* kbuf  = (ushort*)alloc((size_t)4096 * 2048 * 2);
  ushort* vtbuf = (ushort*)alloc((size_t)4096 * 2048 * 2);
  ushort* aobuf = qbuf;  // alias: attn writes exactly the region only it reads
  if (off > ws_size) return;  // ws too small: leaves output zeroed (visible failure)

  // hs f32 -> bf16
  f32_to_bf16_kernel<<<(4096 * 3584 / 4) / 256, 256, 0, stream>>>(hs, hsb, 4096 * 3584 / 4);

  // Q projection
  transpose_f32_bf16<<<(3584 / 64) * (4096 / 64), 256, 0, stream>>>(Wq, wT, 3584, 4096);
  gemm_bt<0><<<32 * 32, 256, 0, stream>>>(hsb, wT, qbuf, 4096, 4096, 3584);

  // K projection
  transpose_f32_bf16<<<(3584 / 64) * (2048 / 64), 256, 0, stream>>>(Wk, wT, 3584, 2048);
  gemm_bt<0><<<32 * 16, 256, 0, stream>>>(hsb, wT, kbuf, 4096, 2048, 3584);

  // V projection (writes V^T layout)
  transpose_f32_bf16<<<(3584 / 64) * (2048 / 64), 256, 0, stream>>>(Wv, wT, 3584, 2048);
  gemm_bt<1><<<32 * 16, 256, 0, stream>>>(hsb, wT, vtbuf, 4096, 2048, 3584);

  // RoPE (q then k), in-place
  rope_kernel<<<(4096 * 16 * 128) / 256, 256, 0, stream>>>(qbuf, sint, cost, 16);
  rope_kernel<<<(4096 * 8 * 128) / 256, 256, 0, stream>>>(kbuf, sint, cost, 8);

  // attention (ao aliases qbuf)
  attn_kernel<<<NB * NHEADS * (NS / 64), 256, 0, stream>>>(qbuf, kbuf, vtbuf, aobuf);

  // output projection, f32 out
  transpose_f32_bf16<<<(4096 / 64) * (3584 / 64), 256, 0, stream>>>(Wo, wT, 4096, 3584);
  gemm_bt<2><<<32 * 28, 256, 0, stream>>>(aobuf, wT, d_out, 4096, 3584, 4096);
}

// Round 6
// 712.575 us; speedup vs baseline: 2.8998x; 1.2870x over previous
//
#include <hip/hip_runtime.h>
#include <hip/hip_bf16.h>

typedef __bf16 bf16x8_t __attribute__((ext_vector_type(8)));
typedef __bf16 bf16x4_t __attribute__((ext_vector_type(4)));
typedef short s16x4_t  __attribute__((ext_vector_type(4)));
typedef float f32x4_t  __attribute__((ext_vector_type(4)));

#define NB 2
#define NS 2048
#define NHID 3584
#define NHEADS 16
#define NKVH 8
#define DH 256
#define WIN 1024

__device__ __forceinline__ float bf2f(ushort u) {
  union { unsigned v; float f; } x; x.v = ((unsigned)u) << 16; return x.f;
}
__device__ __forceinline__ ushort f2bf(float f) {
  unsigned x = __builtin_bit_cast(unsigned, f);
  unsigned r = (x + 0x7fffu + ((x >> 16) & 1u)) >> 16;
  return (ushort)r;
}

__device__ __forceinline__ void gload16(const void* g, void* l) {
  __builtin_amdgcn_global_load_lds((const __attribute__((address_space(1))) void*)g,
                                   (__attribute__((address_space(3))) void*)l, 16, 0, 0);
}

__device__ __forceinline__ f32x4_t mfma_pv(s16x4_t a, s16x4_t b, f32x4_t c) {
#if __has_builtin(__builtin_amdgcn_mfma_f32_16x16x16_bf16)
  return __builtin_amdgcn_mfma_f32_16x16x16_bf16(
      __builtin_bit_cast(bf16x4_t, a), __builtin_bit_cast(bf16x4_t, b), c, 0, 0, 0);
#else
  return __builtin_amdgcn_mfma_f32_16x16x16bf16_1k(a, b, c, 0, 0, 0);
#endif
}

// ---------------- f32 -> bf16 elementwise convert (x4 vectorized) ---------
__global__ __launch_bounds__(256) void f32_to_bf16_kernel(const float* __restrict__ in,
                                                          ushort* __restrict__ out, int n4) {
  int i = (int)blockIdx.x * 256 + (int)threadIdx.x;
  if (i < n4) {
    float4 v = ((const float4*)in)[i];
    ushort4 o;
    o.x = f2bf(v.x); o.y = f2bf(v.y); o.z = f2bf(v.z); o.w = f2bf(v.w);
    ((ushort4*)out)[i] = o;
  }
}

// ------------- transpose+convert: f32 in[R][C] -> bf16 out[C][R] ----------
__global__ __launch_bounds__(256) void transpose_f32_bf16(const float* __restrict__ in,
                                                          ushort* __restrict__ out,
                                                          int R, int Cc) {
  __shared__ ushort tile[64][72];
  const int t = threadIdx.x;
  const int ct = Cc >> 6;
  const int by = blockIdx.x / ct;
  const int bx = blockIdx.x % ct;
  const int r0 = by << 6, c0 = bx << 6;
#pragma unroll
  for (int i = 0; i < 16; ++i) {
    int idx = i * 256 + t;
    int r = idx >> 6, c = idx & 63;
    tile[r][c] = f2bf(in[(size_t)(r0 + r) * Cc + c0 + c]);
  }
  __syncthreads();
#pragma unroll
  for (int i = 0; i < 16; ++i) {
    int idx = i * 256 + t;
    int rr = idx >> 6, cc = idx & 63;
    out[(size_t)(c0 + rr) * R + r0 + cc] = tile[cc][rr];
  }
}

// ---------------- GEMM: C[M][N] = A[M][K] * Bt[N][K]^T, bf16 in, f32 acc
// m97 structure: 128x128 tile, BK=64, 4 waves (2x2), global_load_lds width-16
// staging (linear LDS dest, inverse-swizzled global source chunk=(l&7)^(l>>3)),
// swizzled ds_read_b128 (byte ^= (row&7)<<4). Epilogues bounce through LDS and
// issue wide dwordx4 stores.
// EPI=0: bf16 C[row*N+col]. EPI=1: bf16 vt[(b*8+kvh)*256+d][s]. EPI=2: f32 C.
template <int EPI>
__global__ __launch_bounds__(256, 2) void gemm_bt(const ushort* __restrict__ A,
                                                  const ushort* __restrict__ Bt,
                                                  void* __restrict__ Cout,
                                                  int M, int N, int K) {
  __shared__ alignas(16) char lds[32768];  // lA = lds[0:16K), lB = lds[16K:32K)
  const int t = threadIdx.x;
  const int lane = t & 63;
  const int w = t >> 6;
  const int g = lane >> 4;
  const int lr = lane & 15;
  const int wm = (w >> 1) << 6;
  const int wn = (w & 1) << 6;

  // bijective XCD swizzle (gridDim.x % 8 == 0 for all call sites)
  const int nbn = N >> 7;
  const int nwg = (int)gridDim.x;
  const int bid = (int)blockIdx.x;
  const int swz = (bid & 7) * (nwg >> 3) + (bid >> 3);
  const int bm = swz / nbn, bn = swz % nbn;
  const int m0 = bm << 7, n0 = bn << 7;

  // staging source: wave w stages rows [w*32, w*32+32), 8 rows per issue.
  const int srow = (w << 5) + (lane >> 3);
  const int schunk = (lane & 7) ^ (lane >> 3);
  const ushort* pa = A + (size_t)(m0 + srow) * K + (schunk << 3);
  const ushort* pb = Bt + (size_t)(n0 + srow) * K + (schunk << 3);
  char* ldst = lds + ((w << 5) << 7);  // (w*32)*128 bytes

  f32x4_t acc[4][4] = {};

  const int nkt = K >> 6;
  for (int kt = 0; kt < nkt; ++kt) {
    const int koff = kt << 6;
    __syncthreads();  // previous tile's reads complete before overwrite
#pragma unroll
    for (int j = 0; j < 4; ++j) {
      gload16(pa + (size_t)(j << 3) * K + koff, ldst + (j << 10));
      gload16(pb + (size_t)(j << 3) * K + koff, ldst + 16384 + (j << 10));
    }
    __syncthreads();  // compiler drains vmcnt(0) before s_barrier
#pragma unroll
    for (int ks = 0; ks < 2; ++ks) {
      bf16x8_t af[4], bfv[4];
#pragma unroll
      for (int mi = 0; mi < 4; ++mi) {
        int row = wm + (mi << 4) + lr;
        af[mi] = *(const bf16x8_t*)(lds + (((row << 7) + (ks << 6) + (g << 4)) ^ ((row & 7) << 4)));
      }
#pragma unroll
      for (int nj = 0; nj < 4; ++nj) {
        int row = wn + (nj << 4) + lr;
        bfv[nj] = *(const bf16x8_t*)(lds + 16384 + (((row << 7) + (ks << 6) + (g << 4)) ^ ((row & 7) << 4)));
      }
#pragma unroll
      for (int mi = 0; mi < 4; ++mi)
#pragma unroll
        for (int nj = 0; nj < 4; ++nj)
          acc[mi][nj] = __builtin_amdgcn_mfma_f32_16x16x32_bf16(af[mi], bfv[nj], acc[mi][nj], 0, 0, 0);
    }
  }

  // ---- epilogue: stage whole 128x128 bf16 tile in LDS, then wide stores ----
  __syncthreads();
  if (EPI == 1) {
    // stage TRANSPOSED: lds[col][row]
#pragma unroll
    for (int mi = 0; mi < 4; ++mi)
#pragma unroll
      for (int nj = 0; nj < 4; ++nj) {
        int col = wn + (nj << 4) + lr;
#pragma unroll
        for (int r = 0; r < 4; ++r) {
          int row = wm + (mi << 4) + (g << 2) + r;
          *(ushort*)(lds + (((col << 8) + (row << 1)) ^ ((col & 7) << 4))) = f2bf(acc[mi][nj][r]);
        }
      }
  } else {
#pragma unroll
    for (int mi = 0; mi < 4; ++mi)
#pragma unroll
      for (int nj = 0; nj < 4; ++nj) {
        int col = wn + (nj << 4) + lr;
#pragma unroll
        for (int r = 0; r < 4; ++r) {
          int row = wm + (mi << 4) + (g << 2) + r;
          *(ushort*)(lds + (((row << 8) + (col << 1)) ^ ((row & 7) << 4))) = f2bf(acc[mi][nj][r]);
        }
      }
  }
  __syncthreads();

  if (EPI == 0) {
    ushort* C = (ushort*)Cout;
#pragma unroll
    for (int it = 0; it < 8; ++it) {
      int idx = it * 256 + t;
      int row = idx >> 4, ch = idx & 15;
      uint4 v = *(const uint4*)(lds + (((row << 8) + (ch << 4)) ^ ((row & 7) << 4)));
      *(uint4*)(C + (size_t)(m0 + row) * N + n0 + (ch << 3)) = v;
    }
  } else if (EPI == 1) {
    ushort* C = (ushort*)Cout;
    const int bb = m0 >> 11;
    const int ss = m0 & (NS - 1);
#pragma unroll
    for (int it = 0; it < 8; ++it) {
      int idx = it * 256 + t;
      int dc = idx >> 4, ch = idx & 15;
      uint4 v = *(const uint4*)(lds + (((dc << 8) + (ch << 4)) ^ ((dc & 7) << 4)));
      int gc = n0 + dc;
      int kvh = gc >> 8, d = gc & 255;
      *(uint4*)(C + ((size_t)((bb * NKVH + kvh) * DH + d)) * NS + ss + (ch << 3)) = v;
    }
  } else {
    float* Cf = (float*)Cout;
#pragma unroll
    for (int it = 0; it < 16; ++it) {
      int idx = it * 256 + t;
      int row = idx >> 5, qd = idx & 31;
      ushort4 hv = *(const ushort4*)(lds + (((row << 8) + (qd << 3)) ^ ((row & 7) << 4)));
      float4 fv;
      fv.x = bf2f(hv.x); fv.y = bf2f(hv.y); fv.z = bf2f(hv.z); fv.w = bf2f(hv.w);
      *(float4*)(Cf + (size_t)(m0 + row) * N + n0 + (qd << 2)) = fv;
    }
  }
}

// ---------------- RoPE in-place on bf16 [B*S][nheads*256], pairs (d,d+128) -
__global__ __launch_bounds__(256) void rope_kernel(ushort* __restrict__ buf,
                                                   const float* __restrict__ sint,
                                                   const float* __restrict__ cost,
                                                   int nheads) {
  int idx = (int)blockIdx.x * 256 + (int)threadIdx.x;
  int d = idx & 127;
  int h = (idx >> 7) % nheads;
  int tok = idx / (nheads << 7);
  int pos = tok & (NS - 1);
  float c = cost[pos * DH + d];
  float s = sint[pos * DH + d];
  size_t base = (size_t)tok * ((size_t)nheads * DH) + h * DH + d;
  float x1 = bf2f(buf[base]);
  float x2 = bf2f(buf[base + 128]);
  buf[base] = f2bf(x1 * c - x2 * s);
  buf[base + 128] = f2bf(x2 * c + x1 * s);
}

// ---------------- flash attention, sliding window + softcap ----------------
// grid: B*NH*(S/64); block 256 = 4 waves, each wave 16 q-rows.
// Swapped QK^T: S^T = mfma(K, Q); P^T lands in 16x16x16 A-operand layout.
// Softcap bounds |logit| <= 50 => fixed-max softmax (m = 0): p = exp(cap),
// no max tracking, no rescale; l reduced once at the end.
// K/V double-buffered in LDS via global_load_lds (linear dest + pre-swizzled
// global source); prefetch t+1 issued before compute(t); ONE barrier/iter.
__global__ __launch_bounds__(256) void attn_kernel(const ushort* __restrict__ q,
                                                   const ushort* __restrict__ k,
                                                   const ushort* __restrict__ vt,
                                                   ushort* __restrict__ ao) {
  __shared__ alignas(16) char lK[2][16384];  // [32 keys][256 d], chunk swz (row&7)
  __shared__ alignas(16) char lV[2][16384];  // [256 d][32 keys], chunk swz ((d>>1)&3)
  const int bid = (int)blockIdx.x;
  const int qb = bid & 31;
  const int h = (bid >> 5) & 15;
  const int b = bid >> 9;
  const int kvh = h >> 1;
  const int qb0 = qb << 6;
  const int t = threadIdx.x;
  const int lane = t & 63;
  const int w = t >> 6;
  const int g = lane >> 4;
  const int lr = lane & 15;

  const int qrow = qb0 + (w << 4) + lr;  // this lane's query (B-operand col)
  bf16x8_t qf[8];
  const ushort* qbase = q + (size_t)(b * NS + qrow) * (NHEADS * DH) + h * DH;
#pragma unroll
  for (int ks = 0; ks < 8; ++ks)
    qf[ks] = *(const bf16x8_t*)(qbase + (ks << 5) + (g << 3));

  float l_r = 0.f;
  f32x4_t oacc[16] = {};

  const int qminw = qb0 + (w << 4);
  const int qmaxw = qminw + 15;
  int t_lo = qb0 - (WIN - 1);
  if (t_lo < 0) t_lo = 0;
  t_lo &= ~31;
  const int t_hi = qb0 + 63;

  const ushort* kgb = k + (size_t)(b * NS) * (NKVH * DH) + kvh * DH;
  const ushort* vgb = vt + (size_t)((b * NKVH + kvh) * DH) * NS;

  auto stage = [&](int kt, int bi) {
    char* dk = lK[bi];
    char* dv = lV[bi];
#pragma unroll
    for (int j = 0; j < 4; ++j) {
      // K: wave w stages rows w*8..w*8+7; 2 rows (1KB) per issue.
      int row = (w << 3) + (j << 1) + (lane >> 5);
      int ck = (lane & 31) ^ (row & 7);
      gload16(kgb + (size_t)(kt + row) * (NKVH * DH) + (ck << 3),
              dk + (((w << 3) + (j << 1)) << 9));
      // V^T: wave w stages d-rows w*64..w*64+63; 16 rows (1KB) per issue.
      int dl = (w << 6) + (j << 4) + (lane >> 2);
      int cv = (lane & 3) ^ ((dl >> 1) & 3);
      gload16(vgb + (size_t)dl * NS + kt + (cv << 3),
              dv + (((w << 2) + j) << 10));
    }
  };

  int cur = 0;
  stage(t_lo, 0);
  __syncthreads();

  for (int kt = t_lo; kt <= t_hi; kt += 32) {
    if (kt + 32 <= t_hi) stage(kt + 32, cur ^ 1);  // async prefetch
    const char* lk = lK[cur];
    const char* lv = lV[cur];
#pragma unroll
    for (int sub = 0; sub < 2; ++sub) {
      const int key0 = kt + (sub << 4);
      if (key0 > qmaxw) continue;                    // fully above causal for wave
      if (key0 + 15 < qminw - (WIN - 1)) continue;   // fully below window for wave

      f32x4_t sacc = {};
      __builtin_amdgcn_s_setprio(1);
#pragma unroll
      for (int ks = 0; ks < 8; ++ks) {
        int row = (sub << 4) + lr;
        bf16x8_t kf = *(const bf16x8_t*)(lk + (((row << 9) + (ks << 6) + (g << 4)) ^ ((row & 7) << 4)));
        sacc = __builtin_amdgcn_mfma_f32_16x16x32_bf16(kf, qf[ks], sacc, 0, 0, 0);
      }
      __builtin_amdgcn_s_setprio(0);

      // p = exp(50*tanh(s/50)), s = sacc/16; fixed max m=0 (|cap|<=50 safe)
      float pvv[4];
#pragma unroll
      for (int r = 0; r < 4; ++r) {
        float e = __expf(fminf(sacc[r] * 0.0025f, 80.f));  // e^{2*(s/50)}
        float th = __fdividef(e - 1.f, e + 1.f);
        float p = __expf(50.f * th);
        int key = key0 + (g << 2) + r;
        bool ok = (key <= qrow) && (qrow - key < WIN);
        p = ok ? p : 0.f;
        pvv[r] = p;
        l_r += p;
      }

      s16x4_t pa;
      pa[0] = (short)f2bf(pvv[0]);
      pa[1] = (short)f2bf(pvv[1]);
      pa[2] = (short)f2bf(pvv[2]);
      pa[3] = (short)f2bf(pvv[3]);

      const int kb2 = (sub << 5) + (g << 3);
      __builtin_amdgcn_s_setprio(1);
#pragma unroll
      for (int dt = 0; dt < 16; ++dt) {
        int d = (dt << 4) + lr;
        s16x4_t vf = *(const s16x4_t*)(lv + ((d << 6) + (kb2 ^ (((d >> 1) & 3) << 4))));
        oacc[dt] = mfma_pv(pa, vf, oacc[dt]);
      }
      __builtin_amdgcn_s_setprio(0);
    }
    __syncthreads();  // drains vmcnt: prefetched tile ready; buffers safe
    cur ^= 1;
  }

  // deferred l reduction: sum the 4 lane-groups, then broadcast per q-row
  l_r += __shfl_xor(l_r, 16);
  l_r += __shfl_xor(l_r, 32);
  float dn[4];
#pragma unroll
  for (int r = 0; r < 4; ++r)
    dn[r] = 1.0f / __shfl(l_r, (g << 2) + r);

  const int orow0 = b * NS + qb0 + (w << 4) + (g << 2);
#pragma unroll
  for (int dt = 0; dt < 16; ++dt) {
    int col = h * DH + (dt << 4) + lr;
#pragma unroll
    for (int r = 0; r < 4; ++r) {
      ao[(size_t)(orow0 + r) * (NHEADS * DH) + col] = f2bf(oacc[dt][r] * dn[r]);
    }
  }
}

extern "C" void kernel_launch(void* const* d_in, const int* in_sizes, int n_in,
                              void* d_out, int out_size, void* d_ws, size_t ws_size,
                              hipStream_t stream) {
  const float* hs   = (const float*)d_in[0];
  const float* sint = (const float*)d_in[3];
  const float* cost = (const float*)d_in[4];
  const float* Wq = (const float*)d_in[6];
  const float* Wk = (const float*)d_in[7];
  const float* Wv = (const float*)d_in[8];
  const float* Wo = (const float*)d_in[9];

  char* ws = (char*)d_ws;
  size_t off = 0;
  auto alloc = [&](size_t bytes) {
    char* p = ws + off;
    off += (bytes + 255) & ~(size_t)255;
    return p;
  };
  ushort* hsb   = (ushort*)alloc((size_t)4096 * 3584 * 2);  // hs in bf16
  ushort* wT    = (ushort*)alloc((size_t)4096 * 3584 * 2);  // reused weight^T buffer
  ushort* qbuf  = (ushort*)alloc((size_t)4096 * 4096 * 2);
  ushort* kbuf  = (ushort*)alloc((size_t)4096 * 2048 * 2);
  ushort* vtbuf = (ushort*)alloc((size_t)4096 * 2048 * 2);
  ushort* aobuf = qbuf;  // alias: attn writes exactly the region only it reads
  if (off > ws_size) return;  // ws too small: leaves output zeroed (visible failure)

  // hs f32 -> bf16
  f32_to_bf16_kernel<<<(4096 * 3584 / 4) / 256, 256, 0, stream>>>(hs, hsb, 4096 * 3584 / 4);

  // Q projection
  transpose_f32_bf16<<<(3584 / 64) * (4096 / 64), 256, 0, stream>>>(Wq, wT, 3584, 4096);
  gemm_bt<0><<<32 * 32, 256, 0, stream>>>(hsb, wT, qbuf, 4096, 4096, 3584);

  // K projection
  transpose_f32_bf16<<<(3584 / 64) * (2048 / 64), 256, 0, stream>>>(Wk, wT, 3584, 2048);
  gemm_bt<0><<<32 * 16, 256, 0, stream>>>(hsb, wT, kbuf, 4096, 2048, 3584);

  // V projection (writes V^T layout)
  transpose_f32_bf16<<<(3584 / 64) * (2048 / 64), 256, 0, stream>>>(Wv, wT, 3584, 2048);
  gemm_bt<1><<<32 * 16, 256, 0, stream>>>(hsb, wT, vtbuf, 4096, 2048, 3584);

  // RoPE (q then k), in-place
  rope_kernel<<<(4096 * 16 * 128) / 256, 256, 0, stream>>>(qbuf, sint, cost, 16);
  rope_kernel<<<(4096 * 8 * 128) / 256, 256, 0, stream>>>(kbuf, sint, cost, 8);

  // attention (ao aliases qbuf)
  attn_kernel<<<NB * NHEADS * (NS / 64), 256, 0, stream>>>(qbuf, kbuf, vtbuf, aobuf);

  // output projection, f32 out
  transpose_f32_bf16<<<(4096 / 64) * (3584 / 64), 256, 0, stream>>>(Wo, wT, 4096, 3584);
  gemm_bt<2><<<32 * 28, 256, 0, stream>>>(aobuf, wT, d_out, 4096, 3584, 4096);
}